// Round 1
// baseline (660.837 us; speedup 1.0000x reference)
//
#include <hip/hip_runtime.h>

// SNNDirectionDecoder fused kernel, Round 1 (fp32-exact baseline).
//
// Structure:
//   init_out_kernel : out[b][c] = T * b2[c]   (out is 0xAA-poisoned each call)
//   snn_fused_kernel: per block = (b, 64-h tile):
//     - GEMM cur[t][h] = sum_i x[b,t,i]*W1[h,i] tiled: BT=256 t-chunk,
//       KI=32 i-stage in LDS, per-thread 16t x 4h register tile.
//     - LIF scan over the chunk via intra-wave shfl chain (16 tg steps).
//     - spike counts shfl-reduced, projected through W2 with atomicAdd.
//
// LDS layout notes:
//   xT uses a granule-permuted layout so the 16-consecutive-t compute reads
//   (4x ds_read_b128 per thread) are <=2-way bank conflicted instead of 8-way,
//   and staging writes land on bank == lane%32 (2-way) via a bit-shuffled
//   thread->row map. wT reads are 16-lane broadcasts (conflict-free).

#define B_   256
#define T_   500
#define I_   256
#define H_   512
#define C_   8
#define BETA 0.9f
#define THR  1.0f

#define BH 64     // h per block
#define BT 256    // t per chunk
#define KI 32     // i per LDS stage
#define NKI (I_ / KI)             // 8
#define NCC ((T_ + BT - 1) / BT)  // 2

// element (ii, t) of the x tile lives at this float offset
__device__ __forceinline__ int xoff(int ii, int t) {
  return ii * BT + ((t >> 2) & 3) * 64 + ((t >> 4) << 2) + (t & 3);
}

__global__ void init_out_kernel(const float* __restrict__ b2,
                                float* __restrict__ out) {
  int idx = blockIdx.x * 256 + threadIdx.x;
  if (idx < B_ * C_) out[idx] = (float)T_ * b2[idx & (C_ - 1)];
}

__global__ __launch_bounds__(256) void snn_fused_kernel(
    const float* __restrict__ x, const float* __restrict__ W1,
    const float* __restrict__ b1, const float* __restrict__ W2,
    float* __restrict__ out) {
  __shared__ __align__(16) float xT[KI * BT];   // 32 KB, permuted layout
  __shared__ __align__(16) float wT[KI][BH];    // 8 KB, plain [ii][h]

  const int tid = threadIdx.x;
  const int tg  = tid & 15;   // t-group: t = tg*16 + a, a in 0..15
  const int hg  = tid >> 4;   // h-group: h = h0 + hg*4 + bb
  const int b   = blockIdx.x; // XCD grouping: all hb of one b -> same XCD
  const int h0  = blockIdx.y * BH;

  const float* xb = x + (size_t)b * (T_ * I_);

  // bit-shuffled staging row so that LDS-write bank == lane%32:
  const int l6    = tid & 63;
  const int stg_t = (tid & 3) | ((tid >> 6) << 2) | (((tid >> 2) & 7) << 4) |
                    (((tid >> 5) & 1) << 7);
  (void)l6;
  const int whh = tid & 63, wiq = tid >> 6;   // W1 staging map

  float4 m   = make_float4(0.f, 0.f, 0.f, 0.f);  // membrane for 4 h
  float4 cnt = make_float4(0.f, 0.f, 0.f, 0.f);  // spike counts (own t's)
  const float4 bias = make_float4(b1[h0 + hg * 4 + 0], b1[h0 + hg * 4 + 1],
                                  b1[h0 + hg * 4 + 2], b1[h0 + hg * 4 + 3]);

  for (int cc = 0; cc < NCC; ++cc) {
    const int t0 = cc * BT;

    float4 acc[16];
    #pragma unroll
    for (int a = 0; a < 16; ++a) acc[a] = make_float4(0.f, 0.f, 0.f, 0.f);

    for (int ki = 0; ki < NKI; ++ki) {
      const int i0 = ki * KI;
      __syncthreads();
      // ---- stage x: this thread fills permuted row t = stg_t (32 floats)
      {
        const int tglob = t0 + stg_t;
        if (tglob < T_) {
          const float* xr = xb + (size_t)tglob * I_ + i0;
          #pragma unroll
          for (int q = 0; q < 8; ++q) {
            const float4 v = *(const float4*)(xr + q * 4);
            xT[xoff(q * 4 + 0, stg_t)] = v.x;
            xT[xoff(q * 4 + 1, stg_t)] = v.y;
            xT[xoff(q * 4 + 2, stg_t)] = v.z;
            xT[xoff(q * 4 + 3, stg_t)] = v.w;
          }
        } else {
          #pragma unroll
          for (int ii = 0; ii < KI; ++ii) xT[xoff(ii, stg_t)] = 0.f;
        }
      }
      // ---- stage W1: wT[ii][hh] = W1[h0+hh][i0+ii]
      #pragma unroll
      for (int k = 0; k < 2; ++k) {
        const int iq = wiq + 4 * k;
        const float4 v =
            *(const float4*)(W1 + (size_t)(h0 + whh) * I_ + i0 + iq * 4);
        wT[iq * 4 + 0][whh] = v.x;
        wT[iq * 4 + 1][whh] = v.y;
        wT[iq * 4 + 2][whh] = v.z;
        wT[iq * 4 + 3][whh] = v.w;
      }
      __syncthreads();
      // ---- compute: 16t x 4h per thread, 5 ds_read_b128 per 64 FMA
      #pragma unroll 2
      for (int ii = 0; ii < KI; ++ii) {
        const float4 wv  = *(const float4*)&wT[ii][hg * 4];
        const float4 xa  = *(const float4*)&xT[ii * BT + 0 * 64 + tg * 4];
        const float4 xb4 = *(const float4*)&xT[ii * BT + 1 * 64 + tg * 4];
        const float4 xc  = *(const float4*)&xT[ii * BT + 2 * 64 + tg * 4];
        const float4 xd  = *(const float4*)&xT[ii * BT + 3 * 64 + tg * 4];
        #define SFMA(A_, XS_)                       \
          acc[A_].x = fmaf(XS_, wv.x, acc[A_].x);   \
          acc[A_].y = fmaf(XS_, wv.y, acc[A_].y);   \
          acc[A_].z = fmaf(XS_, wv.z, acc[A_].z);   \
          acc[A_].w = fmaf(XS_, wv.w, acc[A_].w);
        SFMA(0, xa.x)  SFMA(1, xa.y)  SFMA(2, xa.z)  SFMA(3, xa.w)
        SFMA(4, xb4.x) SFMA(5, xb4.y) SFMA(6, xb4.z) SFMA(7, xb4.w)
        SFMA(8, xc.x)  SFMA(9, xc.y)  SFMA(10, xc.z) SFMA(11, xc.w)
        SFMA(12, xd.x) SFMA(13, xd.y) SFMA(14, xd.z) SFMA(15, xd.w)
        #undef SFMA
      }
    }

    // ---- LIF scan over this chunk: serial chain across the 16 tg groups.
    // Lane layout: lane = (hg%4)*16 + tg, so broadcast src = (lane&48) + s.
    #pragma unroll 1
    for (int s = 0; s < 16; ++s) {
      if (tg == s) {
        #pragma unroll
        for (int a = 0; a < 16; ++a) {
          const int t = t0 + s * 16 + a;
          if (t < T_) {
            float r;
            r = (m.x > THR) ? THR : 0.f;
            m.x = fmaf(BETA, m.x, acc[a].x + bias.x) - r;
            if (m.x > THR) cnt.x += 1.f;
            r = (m.y > THR) ? THR : 0.f;
            m.y = fmaf(BETA, m.y, acc[a].y + bias.y) - r;
            if (m.y > THR) cnt.y += 1.f;
            r = (m.z > THR) ? THR : 0.f;
            m.z = fmaf(BETA, m.z, acc[a].z + bias.z) - r;
            if (m.z > THR) cnt.z += 1.f;
            r = (m.w > THR) ? THR : 0.f;
            m.w = fmaf(BETA, m.w, acc[a].w + bias.w) - r;
            if (m.w > THR) cnt.w += 1.f;
          }
        }
      }
      const int src = (tid & 48) + s;
      m.x = __shfl(m.x, src, 64);
      m.y = __shfl(m.y, src, 64);
      m.z = __shfl(m.z, src, 64);
      m.w = __shfl(m.w, src, 64);
    }
  }

  // ---- reduce spike counts across tg (low 4 lane bits)
  #pragma unroll
  for (int mask = 1; mask <= 8; mask <<= 1) {
    cnt.x += __shfl_xor(cnt.x, mask, 64);
    cnt.y += __shfl_xor(cnt.y, mask, 64);
    cnt.z += __shfl_xor(cnt.z, mask, 64);
    cnt.w += __shfl_xor(cnt.w, mask, 64);
  }
  // ---- project through W2 and accumulate into out
  if (tg == 0) {
    #pragma unroll
    for (int c = 0; c < C_; ++c) {
      const float* w2 = W2 + c * H_ + h0 + hg * 4;
      const float p = cnt.x * w2[0] + cnt.y * w2[1] + cnt.z * w2[2] +
                      cnt.w * w2[3];
      atomicAdd(&out[b * C_ + c], p);
    }
  }
}

extern "C" void kernel_launch(void* const* d_in, const int* in_sizes, int n_in,
                              void* d_out, int out_size, void* d_ws,
                              size_t ws_size, hipStream_t stream) {
  (void)in_sizes; (void)n_in; (void)d_ws; (void)ws_size; (void)out_size;
  const float* x  = (const float*)d_in[0];
  const float* W1 = (const float*)d_in[1];
  const float* b1 = (const float*)d_in[2];
  const float* W2 = (const float*)d_in[3];
  const float* b2 = (const float*)d_in[4];
  float* out = (float*)d_out;

  init_out_kernel<<<dim3((B_ * C_ + 255) / 256), dim3(256), 0, stream>>>(b2, out);
  snn_fused_kernel<<<dim3(B_, H_ / BH), dim3(256), 0, stream>>>(x, W1, b1, W2,
                                                                out);
}

// Round 2
// 622.105 us; speedup vs baseline: 1.0623x; 1.0623x over previous
//
#include <hip/hip_runtime.h>

// SNNDirectionDecoder fused kernel, Round 2.
// Changes vs R1 (theory: 224us of non-FMA VALU issue + VGPR=64 spill throttle):
//  - __launch_bounds__(256,4): 128-VGPR budget so acc[16] float4 stays in regs.
//  - bias folded into acc init (scan reads cur directly).
//  - scan restructured: per 128t x 64h half-chunk, dump acc to LDS [t][68]
//    (b128 writes, ~4-way; scalar reads conflict-free), then wave0's 64 lanes
//    scan h=lane in parallel over t (serial only in time, all lanes useful).
//    Replaces the 16-step exec-masked shfl chain (16x issue waste, ~84us).
//  - inner ii loop unrolled with base+immediate ds_reads (no addr VALU).

#define B_   256
#define T_   500
#define I_   256
#define H_   512
#define C_   8
#define BETA 0.9f
#define THR  1.0f

#define BH 64     // h per block
#define BT 256    // t per chunk
#define KI 32     // i per LDS stage
#define NKI (I_ / KI)             // 8
#define NCC ((T_ + BT - 1) / BT)  // 2
#define DSTR 68   // dump row stride in floats (mult of 4 => aligned b128)

// element (ii, t) of the x tile lives at this float offset (permuted layout:
// compute reads are <=2-way conflicted, staging writes land on bank lane%32)
__device__ __forceinline__ int xoff(int ii, int t) {
  return ii * BT + ((t >> 2) & 3) * 64 + ((t >> 4) << 2) + (t & 3);
}

__global__ void init_out_kernel(const float* __restrict__ b2,
                                float* __restrict__ out) {
  int idx = blockIdx.x * 256 + threadIdx.x;
  if (idx < B_ * C_) out[idx] = (float)T_ * b2[idx & (C_ - 1)];
}

__global__ __launch_bounds__(256, 4) void snn_fused_kernel(
    const float* __restrict__ x, const float* __restrict__ W1,
    const float* __restrict__ b1, const float* __restrict__ W2,
    float* __restrict__ out) {
  // GEMM phase: xT = lds[0 .. KI*BT) (32KB, permuted), wT = [KI][BH] (8KB).
  // Scan phase: dmp = lds reused as [128][DSTR] (34816B <= 40960B).
  __shared__ __align__(16) float lds[KI * BT + KI * BH];
  float* xT = lds;
  float* wT = lds + KI * BT;

  const int tid = threadIdx.x;
  const int tg  = tid & 15;   // t-group: t = tg*16 + a
  const int hg  = tid >> 4;   // h-group: h = h0 + hg*4 + component
  const int b   = blockIdx.x;
  const int h0  = blockIdx.y * BH;

  const float* xb = x + (size_t)b * (T_ * I_);

  // bit-shuffled staging row so LDS-write bank == lane%32 (R1: 0 conflicts)
  const int stg_t = (tid & 3) | ((tid >> 6) << 2) | (((tid >> 2) & 7) << 4) |
                    (((tid >> 5) & 1) << 7);
  const int whh = tid & 63, wiq = tid >> 6;   // W1 staging map

  // scan state: wave0 lane = h index (tid<64). Dead regs for other waves.
  float mreg = 0.f, cnt = 0.f;

  const float4 bias = make_float4(b1[h0 + hg * 4 + 0], b1[h0 + hg * 4 + 1],
                                  b1[h0 + hg * 4 + 2], b1[h0 + hg * 4 + 3]);

  for (int cc = 0; cc < NCC; ++cc) {
    const int t0 = cc * BT;

    float4 acc[16];
    #pragma unroll
    for (int a = 0; a < 16; ++a) acc[a] = bias;   // b1 folded in

    for (int ki = 0; ki < NKI; ++ki) {
      const int i0 = ki * KI;
      __syncthreads();   // prev compute / prev scan done before overwrite
      // ---- stage x: fill permuted row t = stg_t (32 floats)
      {
        const int tglob = t0 + stg_t;
        if (tglob < T_) {
          const float* xr = xb + (size_t)tglob * I_ + i0;
          #pragma unroll
          for (int q = 0; q < 8; ++q) {
            const float4 v = *(const float4*)(xr + q * 4);
            xT[xoff(q * 4 + 0, stg_t)] = v.x;
            xT[xoff(q * 4 + 1, stg_t)] = v.y;
            xT[xoff(q * 4 + 2, stg_t)] = v.z;
            xT[xoff(q * 4 + 3, stg_t)] = v.w;
          }
        } else {
          #pragma unroll
          for (int ii = 0; ii < KI; ++ii) xT[xoff(ii, stg_t)] = 0.f;
        }
      }
      // ---- stage W1: wT[ii][hh] = W1[h0+hh][i0+ii]
      #pragma unroll
      for (int k = 0; k < 2; ++k) {
        const int iq = wiq + 4 * k;
        const float4 v =
            *(const float4*)(W1 + (size_t)(h0 + whh) * I_ + i0 + iq * 4);
        wT[(iq * 4 + 0) * BH + whh] = v.x;
        wT[(iq * 4 + 1) * BH + whh] = v.y;
        wT[(iq * 4 + 2) * BH + whh] = v.z;
        wT[(iq * 4 + 3) * BH + whh] = v.w;
      }
      __syncthreads();
      // ---- compute: 16t x 4h per thread; base+imm ds_reads, 64 FMA per ii
      {
        const float* xTb = xT + tg * 4;
        const float* wTb = wT + hg * 4;
        #pragma unroll 8
        for (int ii = 0; ii < KI; ++ii) {
          const float4 wv  = *(const float4*)(wTb + ii * BH);
          const float4 xa  = *(const float4*)(xTb + ii * BT);
          const float4 xb4 = *(const float4*)(xTb + ii * BT + 64);
          const float4 xc  = *(const float4*)(xTb + ii * BT + 128);
          const float4 xd  = *(const float4*)(xTb + ii * BT + 192);
          #define SFMA(A_, XS_)                       \
            acc[A_].x = fmaf(XS_, wv.x, acc[A_].x);   \
            acc[A_].y = fmaf(XS_, wv.y, acc[A_].y);   \
            acc[A_].z = fmaf(XS_, wv.z, acc[A_].z);   \
            acc[A_].w = fmaf(XS_, wv.w, acc[A_].w);
          SFMA(0, xa.x)  SFMA(1, xa.y)  SFMA(2, xa.z)  SFMA(3, xa.w)
          SFMA(4, xb4.x) SFMA(5, xb4.y) SFMA(6, xb4.z) SFMA(7, xb4.w)
          SFMA(8, xc.x)  SFMA(9, xc.y)  SFMA(10, xc.z) SFMA(11, xc.w)
          SFMA(12, xd.x) SFMA(13, xd.y) SFMA(14, xd.z) SFMA(15, xd.w)
          #undef SFMA
        }
      }
    }

    // ---- dump + scan, two 128t halves (reuses lds as dmp[128][DSTR])
    #pragma unroll 1
    for (int half = 0; half < 2; ++half) {
      __syncthreads();   // GEMM reads / prev scan done before dump overwrite
      if ((tg >> 3) == half) {
        const int ltb = (tg & 7) * 16;   // local t base within half
        #pragma unroll
        for (int a = 0; a < 16; ++a) {
          // dmp[ltb+a][hg*4 .. +3] <- acc[a]  (4 h-contiguous floats)
          *(float4*)(lds + (ltb + a) * DSTR + hg * 4) = acc[a];
        }
      }
      __syncthreads();
      if (tid < 64) {   // wave0: lane = h, serial in t only
        const int rem = T_ - (t0 + half * 128);
        const int nt  = rem < 128 ? rem : 128;
        #pragma unroll 4
        for (int j = 0; j < nt; ++j) {
          const float cur = lds[j * DSTR + tid];
          const float r   = (mreg > THR) ? THR : 0.f;
          mreg = fmaf(BETA, mreg, cur) - r;
          if (mreg > THR) cnt += 1.f;
        }
      }
    }
  }

  // ---- projection: wave0 holds cnt[h=lane]; reduce per class, one atomic
  if (tid < 64) {
    #pragma unroll
    for (int c = 0; c < C_; ++c) {
      float p = cnt * W2[c * H_ + h0 + tid];
      #pragma unroll
      for (int mask = 32; mask >= 1; mask >>= 1) p += __shfl_xor(p, mask, 64);
      if (tid == 0) atomicAdd(&out[b * C_ + c], p);
    }
  }
}

extern "C" void kernel_launch(void* const* d_in, const int* in_sizes, int n_in,
                              void* d_out, int out_size, void* d_ws,
                              size_t ws_size, hipStream_t stream) {
  (void)in_sizes; (void)n_in; (void)d_ws; (void)ws_size; (void)out_size;
  const float* x  = (const float*)d_in[0];
  const float* W1 = (const float*)d_in[1];
  const float* b1 = (const float*)d_in[2];
  const float* W2 = (const float*)d_in[3];
  const float* b2 = (const float*)d_in[4];
  float* out = (float*)d_out;

  init_out_kernel<<<dim3((B_ * C_ + 255) / 256), dim3(256), 0, stream>>>(b2, out);
  snn_fused_kernel<<<dim3(B_, H_ / BH), dim3(256), 0, stream>>>(x, W1, b1, W2,
                                                                out);
}

// Round 3
// 310.547 us; speedup vs baseline: 2.1280x; 2.0033x over previous
//
#include <hip/hip_runtime.h>

// SNNDirectionDecoder, Round 3: MFMA fp16-split GEMM + fused LIF scan.
//
// cur[t][h] = sum_i x[t][i]*W1[h][i] computed as
//   acc_hi = xh*wh ; acc_lo = xh*wl' + xl'*wh ; cur = acc_hi + 2^-11*acc_lo
// with xh=fp16(x), xl'=fp16((x-xh)*2^11), same for W1 (all operands normal
// range -> robust to fp16 denormal flush in MFMA). Residual ~2^-22 => cur
// error ~5e-7 rms, comparable to fp32-reorder noise at spike granularity.
//
// Grid: (b, h-half). Block 256 = 4 waves; wave w owns 64t x 64h (h-local
// w*64). Per 64-t chunk: 8 K-steps (BK=32), v_mfma_f32_16x16x32_f16.
// LDS tiles XOR-swizzled so frag ds_read_b128 hit 64 distinct 16B slots.
// W1 split+tiled+swizzled once into d_ws by split_w1_kernel => GEMM W
// staging is a linear coalesced copy. Scan: per-wave dump 32t x 64h to
// [32][68] region, 64 lanes scan h=lane in parallel (wave-local, no
// barriers inside dump/scan).

#define B_   256
#define T_   500
#define I_   256
#define H_   512
#define C_   8

#define TC   64                    // t per chunk
#define BK   32                    // k per step
#define NKS  (I_ / BK)             // 8
#define NCH  ((T_ + TC - 1) / TC)  // 8
#define DSTR 68                    // dump row stride (floats)

#define WTH_OFF 0
#define WTL_OFF 16384
#define XTH_OFF 32768
#define XTL_OFF 36864
// smem total 40960; dump reuses [0, 4*32*DSTR*4 = 34816)

typedef __attribute__((ext_vector_type(8))) _Float16 half8;
typedef __attribute__((ext_vector_type(4))) float f32x4;

union H8 { _Float16 h[8]; float4 v; };

__global__ void init_out_kernel(const float* __restrict__ b2,
                                float* __restrict__ out) {
  int idx = blockIdx.x * 256 + threadIdx.x;
  if (idx < B_ * C_) out[idx] = (float)T_ * b2[idx & (C_ - 1)];
}

// Split W1 into pre-tiled, pre-swizzled fp16 hi/lo images in d_ws.
// Image layout: [kstep][half] blocks of 16KB; within a block, row hl (0..255)
// chunk c (0..3) lives at 16B slot ((hl*4+c) ^ (hl&7)), element e*2 bytes.
// ws: hi at [0, 256KB), lo at [256KB, 512KB).
__global__ void split_w1_kernel(const float* __restrict__ W1,
                                char* __restrict__ ws) {
  int idx = blockIdx.x * 256 + threadIdx.x;
  if (idx >= H_ * I_) return;
  const int h = idx >> 8, i = idx & 255;
  const float w = W1[h * I_ + i];
  const _Float16 hi = (_Float16)w;
  const _Float16 lo = (_Float16)((w - (float)hi) * 2048.0f);
  const int kstep = i >> 5, kk = i & 31, c = kk >> 3, e = kk & 7;
  const int half = h >> 8, hl = h & 255;
  const int slot = ((hl << 2) + c) ^ (hl & 7);
  const size_t off =
      ((size_t)((kstep << 1) + half) << 14) + ((size_t)slot << 4) + (e << 1);
  *(_Float16*)(ws + off) = hi;
  *(_Float16*)(ws + 262144 + off) = lo;
}

__global__ __launch_bounds__(256, 2) void snn_mfma_kernel(
    const float* __restrict__ x, const char* __restrict__ ws,
    const float* __restrict__ b1, const float* __restrict__ W2,
    float* __restrict__ out) {
  __shared__ __align__(16) char smem[40960];

  const int tid  = threadIdx.x;
  const int b    = blockIdx.x;
  const int half = blockIdx.y;   // h-half: h = half*256 + local

  const int l  = tid & 63;       // lane
  const int wv = tid >> 6;       // wave id = h-block (64 h each)
  const int cc = l >> 4;         // k-chunk of fragment
  const int rr = l & 15;         // row-in-tile
  const int sw = rr & 7;

  // fragment byte offsets (swizzled, conflict-free bijection over lanes)
  int offA[4], offB[4];
  #pragma unroll
  for (int i = 0; i < 4; ++i)
    offA[i] = (((i << 6) + (rr << 2) + cc) ^ sw) << 4;
  #pragma unroll
  for (int j = 0; j < 4; ++j)
    offB[j] = (((wv << 8) + (j << 6) + (rr << 2) + cc) ^ sw) << 4;

  // x staging map: thread -> (row xt, chunk xc), swizzled slot
  const int xc = tid & 3, xt = tid >> 2;
  const int xslot = (((xt << 2) + xc) ^ (xt & 7)) << 4;

  const float* xb = x + (size_t)b * (T_ * I_);
  const float biash = b1[(half << 8) + (wv << 6) + l];

  float mreg = 0.f, cnt = 0.f;

  #pragma unroll 1
  for (int ch = 0; ch < NCH; ++ch) {
    const int t0 = ch * TC;

    f32x4 acch[4][4], accl[4][4];
    #pragma unroll
    for (int i = 0; i < 4; ++i)
      #pragma unroll
      for (int j = 0; j < 4; ++j) {
        acch[i][j] = (f32x4){0.f, 0.f, 0.f, 0.f};
        accl[i][j] = (f32x4){0.f, 0.f, 0.f, 0.f};
      }

    #pragma unroll 1
    for (int ks = 0; ks < NKS; ++ks) {
      __syncthreads();   // prior compute/scan reads done before overwrite
      // ---- stage W (linear copy of pre-swizzled 16KB blocks)
      {
        const char* gh = ws + (((size_t)((ks << 1) + half)) << 14);
        const char* gl = gh + 262144;
        #pragma unroll
        for (int qq = 0; qq < 4; ++qq) {
          const int o = (tid << 4) + (qq << 12);
          *(float4*)(smem + WTH_OFF + o) = *(const float4*)(gh + o);
          *(float4*)(smem + WTL_OFF + o) = *(const float4*)(gl + o);
        }
      }
      // ---- stage x: fp32 -> (hi, lo*2^11) fp16, swizzled slots
      {
        H8 h8, l8;
        const int tg = t0 + xt;
        if (tg < T_) {
          const float* xr = xb + (size_t)tg * I_ + (ks << 5) + (xc << 3);
          const float4 a  = *(const float4*)xr;
          const float4 b4 = *(const float4*)(xr + 4);
          const float av[8] = {a.x, a.y, a.z, a.w, b4.x, b4.y, b4.z, b4.w};
          #pragma unroll
          for (int e = 0; e < 8; ++e) {
            const _Float16 hh = (_Float16)av[e];
            h8.h[e] = hh;
            l8.h[e] = (_Float16)((av[e] - (float)hh) * 2048.0f);
          }
        } else {
          #pragma unroll
          for (int e = 0; e < 8; ++e) { h8.h[e] = (_Float16)0.f; l8.h[e] = (_Float16)0.f; }
        }
        *(float4*)(smem + XTH_OFF + xslot) = h8.v;
        *(float4*)(smem + XTL_OFF + xslot) = l8.v;
      }
      __syncthreads();
      // ---- fragments + 48 MFMA
      half8 ah[4], al[4], bh[4], bl[4];
      #pragma unroll
      for (int i = 0; i < 4; ++i) {
        ah[i] = *(const half8*)(smem + XTH_OFF + offA[i]);
        al[i] = *(const half8*)(smem + XTL_OFF + offA[i]);
      }
      #pragma unroll
      for (int j = 0; j < 4; ++j) {
        bh[j] = *(const half8*)(smem + WTH_OFF + offB[j]);
        bl[j] = *(const half8*)(smem + WTL_OFF + offB[j]);
      }
      #pragma unroll
      for (int i = 0; i < 4; ++i)
        #pragma unroll
        for (int j = 0; j < 4; ++j)
          acch[i][j] = __builtin_amdgcn_mfma_f32_16x16x32_f16(
              ah[i], bh[j], acch[i][j], 0, 0, 0);
      #pragma unroll
      for (int i = 0; i < 4; ++i)
        #pragma unroll
        for (int j = 0; j < 4; ++j) {
          accl[i][j] = __builtin_amdgcn_mfma_f32_16x16x32_f16(
              ah[i], bl[j], accl[i][j], 0, 0, 0);
          accl[i][j] = __builtin_amdgcn_mfma_f32_16x16x32_f16(
              al[i], bh[j], accl[i][j], 0, 0, 0);
        }
    }

    __syncthreads();   // all frag reads done before dump overwrites tiles

    // ---- dump + scan, two 32-t halves; wave-local region [32][DSTR]
    float* dmp = (float*)smem + wv * (32 * DSTR);
    #pragma unroll
    for (int ht = 0; ht < 2; ++ht) {
      #pragma unroll
      for (int i2 = 0; i2 < 2; ++i2) {
        const int i = (ht << 1) + i2;
        #pragma unroll
        for (int j = 0; j < 4; ++j)
          #pragma unroll
          for (int r = 0; r < 4; ++r) {
            const int tl = (i2 << 4) + ((l >> 4) << 2) + r;
            dmp[tl * DSTR + (j << 4) + rr] =
                acch[i][j][r] + 4.8828125e-4f * accl[i][j][r];
          }
      }
      // scan: lane = h-local, serial in t (lgkmcnt orders wave-local LDS)
      const int base = t0 + (ht << 5);
      int nt = T_ - base; nt = nt < 32 ? nt : 32;
      #pragma unroll 1
      for (int jj = 0; jj < nt; ++jj) {
        const float cur = dmp[jj * DSTR + l] + biash;
        const float rst = (mreg > 1.0f) ? 1.0f : 0.0f;
        mreg = fmaf(0.9f, mreg, cur) - rst;
        if (mreg > 1.0f) cnt += 1.0f;
      }
    }
  }

  // ---- projection: cnt[h=lane] -> out[b][c], one atomic per (wave, c)
  const int hglob = (half << 8) + (wv << 6) + l;
  #pragma unroll
  for (int c = 0; c < C_; ++c) {
    float p = cnt * W2[c * H_ + hglob];
    #pragma unroll
    for (int m = 32; m >= 1; m >>= 1) p += __shfl_xor(p, m, 64);
    if (l == 0) atomicAdd(&out[b * C_ + c], p);
  }
}

extern "C" void kernel_launch(void* const* d_in, const int* in_sizes, int n_in,
                              void* d_out, int out_size, void* d_ws,
                              size_t ws_size, hipStream_t stream) {
  (void)in_sizes; (void)n_in; (void)ws_size; (void)out_size;
  const float* x  = (const float*)d_in[0];
  const float* W1 = (const float*)d_in[1];
  const float* b1 = (const float*)d_in[2];
  const float* W2 = (const float*)d_in[3];
  const float* b2 = (const float*)d_in[4];
  float* out = (float*)d_out;
  char* ws = (char*)d_ws;   // needs 512 KB (2 x 256 KB fp16 W1 split images)

  init_out_kernel<<<dim3((B_ * C_ + 255) / 256), dim3(256), 0, stream>>>(b2, out);
  split_w1_kernel<<<dim3((H_ * I_ + 255) / 256), dim3(256), 0, stream>>>(W1, ws);
  snn_mfma_kernel<<<dim3(B_, 2), dim3(256), 0, stream>>>(x, ws, b1, W2, out);
}

// Round 5
// 261.176 us; speedup vs baseline: 2.5302x; 1.1890x over previous
//
#include <hip/hip_runtime.h>

// SNNDirectionDecoder, Round 5 = Round 4 with the cvt_pkrtz type fix.
//
// Key algebra: scan the scaled system mem' = 16*mem (THR'=16, reset 16, cur' =
// x@(16*W1)^T + 16*b1) -- exactly equivalent to the reference in real
// arithmetic. With W' = 16*W1 ~ N(0,1), BOTH split residuals
//   xl = x - fp16(x)        (~1e-4, normal fp16 range)
//   wl = W' - fp16(W')      (~2.4e-4, normal fp16 range)
// need no 2^11 scaling, so all three products (xh*wh + xl*wh + xh*wl)
// accumulate into ONE fp32 accumulator. Missing xl*wl term ~1e-5 relative.
//
// Structure: grid (b, h-half). Block 256 = 4 waves; wave wv owns 128t x 64h.
// 32 rounds (4 chunks x 8 k-steps of BK=32). Per round:
//   [issue x glb loads r+1] -> frag reads + 96 MFMA -> (ks==7: dump+scan,
//   wave-local, overlays own B region) -> barA -> [W-DMA r+1 via
//   global_load_lds from pre-swizzled ws; cvt+ds_write x r+1] -> barB.
// LDS = 64KB exactly (W 32K single-buf + x 2x16K dbuf) -> 2 blocks/CU.
// All frag reads / dump writes / scan reads verified 8 lanes per bank-group
// (conflict-free) via slot(n) = n ^ (row & 7) XOR swizzle on 16B granules.

#define B_   256
#define T_   500
#define I_   256
#define H_   512
#define C_   8

#define TC   128
#define BK   32
#define NKS  8                 // I_/BK
#define NCH  4                 // chunks of TC covering 512 (t>=500 masked)
#define NR   (NCH * NKS)       // 32 rounds

// LDS byte map (total 65536)
#define WBUF  0                // 32KB: hi [0,16K), lo [16K,32K); dump overlays
#define XBUF0 32768            // 16KB: hi 8K, lo 8K
#define XBUF1 49152

typedef __attribute__((ext_vector_type(8))) _Float16 half8;
typedef __attribute__((ext_vector_type(2))) __fp16 f16x2;
typedef __attribute__((ext_vector_type(4))) float f32x4;

typedef __attribute__((address_space(1))) const unsigned int as1_uint;
typedef __attribute__((address_space(3))) unsigned int as3_uint;

__device__ __forceinline__ void lds_dma16(const void* g, void* l) {
  __builtin_amdgcn_global_load_lds((as1_uint*)g, (as3_uint*)l, 16, 0, 0);
}

#define MFMA16(A, B, Cc) __builtin_amdgcn_mfma_f32_16x16x32_f16(A, B, Cc, 0, 0, 0)

__global__ void init_out_kernel(const float* __restrict__ b2,
                                float* __restrict__ out) {
  int idx = blockIdx.x * 256 + threadIdx.x;
  if (idx < B_ * C_) out[idx] = (float)T_ * b2[idx & (C_ - 1)];
}

// Pre-split W' = 16*W1 into fp16 hi/lo, tiled+swizzled so the main kernel's
// W staging is a LINEAR global_load_lds DMA. ws block (ks,half) = 32KB:
// hi 16KB + lo 16KB; 16B slot ((hl*4+c) ^ (hl&7)) holds W'[h][ks*32+c*8+e].
__global__ void split_w1_kernel(const float* __restrict__ W1,
                                char* __restrict__ ws) {
  const int n = blockIdx.x * 256 + threadIdx.x;   // 16384 slots
  if (n >= H_ * NKS * 4) return;
  const int h = n >> 5, ks = (n >> 2) & 7, c = n & 3;
  const float* src = W1 + h * I_ + ks * BK + c * 8;
  union { half8 v; _Float16 e[8]; } hi, lo;
  #pragma unroll
  for (int e = 0; e < 8; ++e) {
    const float w = 16.0f * src[e];
    const _Float16 wh = (_Float16)w;
    hi.e[e] = wh;
    lo.e[e] = (_Float16)(w - (float)wh);
  }
  const int slot = (((h & 255) << 2) + c) ^ (h & 7);
  char* dst = ws + (size_t)((ks << 1) + (h >> 8)) * 32768 + ((size_t)slot << 4);
  *(half8*)dst = hi.v;
  *(half8*)(dst + 16384) = lo.v;
}

__device__ __forceinline__ void load_x16(const float* xb, int t, int ib,
                                         float* a) {
  if (t < T_) {
    const float* xr = xb + (size_t)t * I_ + ib;
    #pragma unroll
    for (int q = 0; q < 4; ++q) {
      const float4 v = *(const float4*)(xr + 4 * q);
      a[4 * q + 0] = v.x; a[4 * q + 1] = v.y;
      a[4 * q + 2] = v.z; a[4 * q + 3] = v.w;
    }
  } else {
    #pragma unroll
    for (int e = 0; e < 16; ++e) a[e] = 0.f;
  }
}

__device__ __forceinline__ void cvt_store_x(char* dstbase, int xs0, int xs1,
                                            const float* a) {
  union { half8 v; f16x2 p[4]; } h0, h1, l0, l1;
  #pragma unroll
  for (int k = 0; k < 4; ++k) {
    const f16x2 ha = __builtin_amdgcn_cvt_pkrtz(a[2 * k], a[2 * k + 1]);
    h0.p[k] = ha;
    l0.p[k] = __builtin_amdgcn_cvt_pkrtz(a[2 * k] - (float)ha[0],
                                         a[2 * k + 1] - (float)ha[1]);
    const f16x2 hb = __builtin_amdgcn_cvt_pkrtz(a[8 + 2 * k], a[9 + 2 * k]);
    h1.p[k] = hb;
    l1.p[k] = __builtin_amdgcn_cvt_pkrtz(a[8 + 2 * k] - (float)hb[0],
                                         a[9 + 2 * k] - (float)hb[1]);
  }
  *(half8*)(dstbase + xs0) = h0.v;
  *(half8*)(dstbase + xs1) = h1.v;
  *(half8*)(dstbase + 8192 + xs0) = l0.v;
  *(half8*)(dstbase + 8192 + xs1) = l1.v;
}

__global__ __launch_bounds__(256, 2) void snn_mfma2(
    const float* __restrict__ x, const char* __restrict__ ws,
    const float* __restrict__ b1, const float* __restrict__ W2,
    float* __restrict__ out) {
  __shared__ __align__(16) char smem[65536];

  const int tid = threadIdx.x;
  const int b = blockIdx.x, half = blockIdx.y;
  const int l = tid & 63, wv = tid >> 6;
  const int rr = l & 15, cc = l >> 4;

  const float* xb = x + (size_t)b * (T_ * I_);

  // fragment swizzled sub-offset (bytes): slot low bits ((rr*4+cc)^(rr&7))
  const int fsw = (((rr << 2) + cc) ^ (rr & 7)) << 4;

  // x staging map: thread -> (row tl, i-half ih)
  const int tl = tid >> 1, ih = tid & 1;
  const int xs0 = ((((tl << 2) + ih * 2 + 0) ^ (tl & 7)) << 4);
  const int xs1 = ((((tl << 2) + ih * 2 + 1) ^ (tl & 7)) << 4);

  const float bias16 = 16.0f * b1[half * 256 + wv * 64 + l];
  float mreg = 0.f, cnt = 0.f;

  f32x4 acc[8][4];
  #pragma unroll
  for (int i = 0; i < 8; ++i)
    #pragma unroll
    for (int j = 0; j < 4; ++j) acc[i][j] = (f32x4){0.f, 0.f, 0.f, 0.f};

  // ---- prologue: stage round 0 (W ks=0 via DMA, x chunk0/ks0)
  {
    const char* wg = ws + (size_t)half * 32768;   // ks=0 block
    #pragma unroll
    for (int q = 0; q < 8; ++q)
      lds_dma16(wg + (wv * 8 + q) * 1024 + l * 16,
                smem + WBUF + (wv * 8 + q) * 1024);
    float a16[16];
    load_x16(xb, tl, ih * 16, a16);
    cvt_store_x(smem + XBUF0, xs0, xs1, a16);
    __syncthreads();
  }

  #pragma unroll 1
  for (int r = 0; r < NR; ++r) {
    const int ks = r & 7, chunk = r >> 3;
    const int xcur = XBUF0 + (r & 1) * 16384;
    const int xnxt = XBUF0 + ((r + 1) & 1) * 16384;
    const bool do_stage = (r + 1 < NR);

    // A) early-issue next round's x global loads (covered by MFMA body)
    float a16[16];
    if (do_stage) {
      const int t1 = ((r + 1) >> 3) * TC + tl;
      load_x16(xb, t1, ((r + 1) & 7) * BK + ih * 16, a16);
    }

    // B) fragment reads + 96 MFMA (3 products, single accumulator)
    half8 ah[8], al[8], bh[4], bl[4];
    #pragma unroll
    for (int i = 0; i < 8; ++i) {
      ah[i] = *(const half8*)(smem + xcur + i * 1024 + fsw);
      al[i] = *(const half8*)(smem + xcur + 8192 + i * 1024 + fsw);
    }
    #pragma unroll
    for (int j = 0; j < 4; ++j) {
      bh[j] = *(const half8*)(smem + WBUF + wv * 4096 + j * 1024 + fsw);
      bl[j] = *(const half8*)(smem + WBUF + 16384 + wv * 4096 + j * 1024 + fsw);
    }
    #pragma unroll
    for (int i = 0; i < 8; ++i)
      #pragma unroll
      for (int j = 0; j < 4; ++j) {
        acc[i][j] = MFMA16(ah[i], bh[j], acc[i][j]);
        acc[i][j] = MFMA16(al[i], bh[j], acc[i][j]);
        acc[i][j] = MFMA16(ah[i], bl[j], acc[i][j]);
      }

    // C) chunk end: dump + LIF scan, wave-local in OWN B-frag region of WBUF
    if (ks == 7) {
      asm volatile("" ::: "memory");   // keep frag reads above dump writes
      const int t0 = chunk * TC;
      #pragma unroll
      for (int p = 0; p < 4; ++p) {
        #pragma unroll
        for (int i2 = 0; i2 < 2; ++i2) {
          #pragma unroll
          for (int j = 0; j < 4; ++j) {
            const int rl = j * 16 + rr;                // h-local row
            const int g = i2 * 4 + cc;                 // t granule in pass
            const int ad = (rl >> 5) * 16384 + wv * 4096 + (rl & 31) * 128 +
                           ((g ^ (rl & 7)) << 4);
            *(f32x4*)(smem + ad) = acc[2 * p + i2][j];
          }
        }
        const int nt = T_ - (t0 + 32 * p) < 32 ? T_ - (t0 + 32 * p) : 32;
        const int rb = (l >> 5) * 16384 + wv * 4096 + (l & 31) * 128;
        #pragma unroll
        for (int g = 0; g < 8; ++g) {
          if (4 * g < nt) {
            const float4 v =
                *(const float4*)(smem + rb + ((g ^ (l & 7)) << 4));
            const float cv[4] = {v.x, v.y, v.z, v.w};
            #pragma unroll
            for (int e = 0; e < 4; ++e) {
              const float curv = cv[e] + bias16;
              const float rst = (mreg > 16.0f) ? 16.0f : 0.f;
              mreg = fmaf(0.9f, mreg, curv) - rst;
              if (mreg > 16.0f) cnt += 1.f;
            }
          }
        }
      }
      #pragma unroll
      for (int i = 0; i < 8; ++i)
        #pragma unroll
        for (int j = 0; j < 4; ++j) acc[i][j] = (f32x4){0.f, 0.f, 0.f, 0.f};
    }

    __syncthreads();   // barA: all reads of Wbuf/xbuf[cur] + scans done

    if (do_stage) {
      // W-DMA for round r+1 (re-staged each chunk; ws is L2-resident)
      const char* wg = ws + (size_t)((((r + 1) & 7) << 1) + half) * 32768;
      #pragma unroll
      for (int q = 0; q < 8; ++q)
        lds_dma16(wg + (wv * 8 + q) * 1024 + l * 16,
                  smem + WBUF + (wv * 8 + q) * 1024);
      cvt_store_x(smem + xnxt, xs0, xs1, a16);
    }
    __syncthreads();   // barB: DMA drained (compiler vmcnt(0)) + x visible
  }

  // ---- projection: cnt[h] @ W2 -> out[b][c]
  const int hglob = half * 256 + wv * 64 + l;
  #pragma unroll
  for (int c = 0; c < C_; ++c) {
    float p = cnt * W2[c * H_ + hglob];
    #pragma unroll
    for (int m = 32; m >= 1; m >>= 1) p += __shfl_xor(p, m, 64);
    if (l == 0) atomicAdd(&out[b * C_ + c], p);
  }
}

extern "C" void kernel_launch(void* const* d_in, const int* in_sizes, int n_in,
                              void* d_out, int out_size, void* d_ws,
                              size_t ws_size, hipStream_t stream) {
  (void)in_sizes; (void)n_in; (void)ws_size; (void)out_size;
  const float* x  = (const float*)d_in[0];
  const float* W1 = (const float*)d_in[1];
  const float* b1 = (const float*)d_in[2];
  const float* W2 = (const float*)d_in[3];
  const float* b2 = (const float*)d_in[4];
  float* out = (float*)d_out;
  char* ws = (char*)d_ws;   // 512 KB: 16 blocks x 32KB (ks x half, hi|lo)

  init_out_kernel<<<dim3((B_ * C_ + 255) / 256), dim3(256), 0, stream>>>(b2, out);
  split_w1_kernel<<<dim3(H_ * NKS * 4 / 256), dim3(256), 0, stream>>>(W1, ws);
  snn_mfma2<<<dim3(B_, 2), dim3(256), 0, stream>>>(x, ws, b1, W2, out);
}

// Round 6
// 249.612 us; speedup vs baseline: 2.6475x; 1.0463x over previous
//
#include <hip/hip_runtime.h>

// SNNDirectionDecoder, Round 6: canonical-linear LDS layouts (conflict fix).
//
// Same algorithm as R5 (fp16-split 3-product MFMA, scaled-by-16 LIF scan,
// absmax 0.25 passing). Changes:
//  - ALL LDS instructions are now the canonical conflict-free class:
//    lane l <-> 16B chunk l of a contiguous region (m134's measured-0 class).
//    * A/B tiles: 1KB granule-tiles, slot = kchunk*16 + row == MFMA lane id.
//      Frag reads: base + i*1024 + l*16 (byte-linear).
//    * x staging writes: base + tile*1024 + l*16 (thread map inverted).
//    * dump/scan: per-wave [tg][64 h-granule] rows; dump instr = contiguous
//      128B per 8-lane group; scan read = row + l*16.
//  - dump overlays xnxt (dead x buffer) instead of WBUF.
//  - bias folded into acc init (per-j bias); scan chain = fma->sub->cmp.
//  - reset_t == spike_{t-1} identity replaces the old-mem compare.

#define B_   256
#define T_   500
#define I_   256
#define H_   512
#define C_   8

#define TC   128
#define BK   32
#define NKS  8                 // I_/BK
#define NCH  4
#define NR   (NCH * NKS)       // 32

// LDS byte map (total 65536)
#define WBUF  0                // 32KB: hi 16K + lo 16K, one k-step, DMA/round
#define XBUF0 32768            // 16KB: hi 8K + lo 8K
#define XBUF1 49152

typedef __attribute__((ext_vector_type(8))) _Float16 half8;
typedef __attribute__((ext_vector_type(2))) __fp16 f16x2;
typedef __attribute__((ext_vector_type(4))) float f32x4;

typedef __attribute__((address_space(1))) const unsigned int as1_uint;
typedef __attribute__((address_space(3))) unsigned int as3_uint;

__device__ __forceinline__ void lds_dma16(const void* g, void* l) {
  __builtin_amdgcn_global_load_lds((as1_uint*)g, (as3_uint*)l, 16, 0, 0);
}

#define MFMA16(A, B, Cc) __builtin_amdgcn_mfma_f32_16x16x32_f16(A, B, Cc, 0, 0, 0)

__global__ void init_out_kernel(const float* __restrict__ b2,
                                float* __restrict__ out) {
  int idx = blockIdx.x * 256 + threadIdx.x;
  if (idx < B_ * C_) out[idx] = (float)T_ * b2[idx & (C_ - 1)];
}

// W' = 16*W1 split to fp16 hi/lo, stored so the main kernel's LDS image is
// granule n (16B) at ws + block*32768 + n*16 (hi; lo at +16384), where
// block = ks*2 + half and within-block granule r = wv*256 + j*64 + c*16 + rr
// holds W'[half*256 + wv*64 + j*16 + rr][ks*32 + c*8 .. +8].
__global__ void split_w1_kernel(const float* __restrict__ W1,
                                char* __restrict__ ws) {
  const int n = blockIdx.x * 256 + threadIdx.x;   // 16384 granules
  if (n >= H_ * NKS * 4) return;
  const int blk = n >> 10, r = n & 1023;
  const int ks = blk >> 1, hh = blk & 1;
  const int h = hh * 256 + (r >> 8) * 64 + ((r >> 6) & 3) * 16 + (r & 15);
  const int c = (r >> 4) & 3;
  const float* src = W1 + h * I_ + ks * BK + c * 8;
  union { half8 v; _Float16 e[8]; } hi, lo;
  #pragma unroll
  for (int e = 0; e < 8; ++e) {
    const float w = 16.0f * src[e];
    const _Float16 wh = (_Float16)w;
    hi.e[e] = wh;
    lo.e[e] = (_Float16)(w - (float)wh);
  }
  char* dst = ws + (size_t)blk * 32768 + (size_t)r * 16;
  *(half8*)dst = hi.v;                 // consecutive n -> consecutive 16B
  *(half8*)(dst + 16384) = lo.v;
}

__device__ __forceinline__ void load_x8(const float* xb, int t, int col,
                                        float* a) {
  if (t < T_) {
    const float* p = xb + (size_t)t * I_ + col;
    const float4 v0 = *(const float4*)p;
    const float4 v1 = *(const float4*)(p + 4);
    a[0] = v0.x; a[1] = v0.y; a[2] = v0.z; a[3] = v0.w;
    a[4] = v1.x; a[5] = v1.y; a[6] = v1.z; a[7] = v1.w;
  } else {
    #pragma unroll
    for (int e = 0; e < 8; ++e) a[e] = 0.f;
  }
}

__device__ __forceinline__ void cvt_store(char* base, int tt, int l,
                                          const float* a) {
  union { half8 v; f16x2 p[4]; } h8, l8;
  #pragma unroll
  for (int k = 0; k < 4; ++k) {
    const f16x2 ha = __builtin_amdgcn_cvt_pkrtz(a[2 * k], a[2 * k + 1]);
    h8.p[k] = ha;
    l8.p[k] = __builtin_amdgcn_cvt_pkrtz(a[2 * k] - (float)ha[0],
                                         a[2 * k + 1] - (float)ha[1]);
  }
  *(half8*)(base + tt * 1024 + l * 16) = h8.v;          // linear per instr
  *(half8*)(base + 8192 + tt * 1024 + l * 16) = l8.v;
}

__global__ __launch_bounds__(256, 2) void snn_mfma3(
    const float* __restrict__ x, const char* __restrict__ ws,
    const float* __restrict__ b1, const float* __restrict__ W2,
    float* __restrict__ out) {
  __shared__ __align__(16) char smem[65536];

  const int tid = threadIdx.x;
  const int b = blockIdx.x, hf = blockIdx.y;
  const int l = tid & 63, wv = tid >> 6;

  const float* xb = x + (size_t)b * (T_ * I_);

  // x staging source: this thread covers tiles 2wv, 2wv+1; row l&15, kchunk l>>4
  const int xrow = l & 15;
  const int xcolb = (l >> 4) * 8;

  // per-j bias (acc h-col = j*16 + (l&15)); scan h = wv*64 + l
  float biasj[4];
  #pragma unroll
  for (int j = 0; j < 4; ++j)
    biasj[j] = 16.0f * b1[hf * 256 + wv * 64 + j * 16 + (l & 15)];

  float mreg = 0.f, cnt = 0.f;
  bool sp = false;

  f32x4 acc[8][4];
  #pragma unroll
  for (int i = 0; i < 8; ++i)
    #pragma unroll
    for (int j = 0; j < 4; ++j)
      acc[i][j] = (f32x4){biasj[j], biasj[j], biasj[j], biasj[j]};

  // ---- prologue: W ks0 DMA + x chunk0/ks0 into XBUF0
  {
    const char* wg = ws + (size_t)hf * 32768;
    #pragma unroll
    for (int q = 0; q < 4; ++q) {
      const int o = (q * 256 + tid) * 16;
      lds_dma16(wg + o, smem + WBUF + o);
      lds_dma16(wg + 16384 + o, smem + WBUF + 16384 + o);
    }
    float a8[2][8];
    load_x8(xb, 2 * wv * 16 + xrow, xcolb, a8[0]);
    load_x8(xb, (2 * wv + 1) * 16 + xrow, xcolb, a8[1]);
    cvt_store(smem + XBUF0, 2 * wv, l, a8[0]);
    cvt_store(smem + XBUF0, 2 * wv + 1, l, a8[1]);
    __syncthreads();
  }

  #pragma unroll 1
  for (int r = 0; r < NR; ++r) {
    const int ks = r & 7;
    const int xcur = XBUF0 + (r & 1) * 16384;
    const int xnxt = XBUF0 + ((r + 1) & 1) * 16384;
    const bool do_stage = (r + 1 < NR);

    // A) early-issue next round's x global loads (regs only)
    float a8[2][8];
    if (do_stage) {
      const int t1 = ((r + 1) >> 3) * TC, c1 = ((r + 1) & 7) * BK + xcolb;
      load_x8(xb, t1 + 2 * wv * 16 + xrow, c1, a8[0]);
      load_x8(xb, t1 + (2 * wv + 1) * 16 + xrow, c1, a8[1]);
    }

    // B) frag reads (all byte-linear: base + i*1024 + l*16) + 96 MFMA
    half8 ah[8], al[8], bh[4], bl[4];
    #pragma unroll
    for (int i = 0; i < 8; ++i) {
      ah[i] = *(const half8*)(smem + xcur + i * 1024 + (l << 4));
      al[i] = *(const half8*)(smem + xcur + 8192 + i * 1024 + (l << 4));
    }
    #pragma unroll
    for (int j = 0; j < 4; ++j) {
      bh[j] = *(const half8*)(smem + WBUF + (wv << 12) + (j << 10) + (l << 4));
      bl[j] = *(const half8*)(smem + WBUF + 16384 + (wv << 12) + (j << 10) +
                              (l << 4));
    }
    #pragma unroll
    for (int i = 0; i < 8; ++i)
      #pragma unroll
      for (int j = 0; j < 4; ++j) {
        acc[i][j] = MFMA16(ah[i], bh[j], acc[i][j]);
        acc[i][j] = MFMA16(al[i], bh[j], acc[i][j]);
        acc[i][j] = MFMA16(ah[i], bl[j], acc[i][j]);
      }

    // C) chunk end: dump + scan in own 4KB of xnxt (dead buffer here)
    if (ks == 7) {
      asm volatile("" ::: "memory");
      const int t0 = (r >> 3) * TC;
      char* dw = smem + xnxt + (wv << 12);
      #pragma unroll
      for (int p = 0; p < 8; ++p) {
        // dump: granule (h = j*16+(l&15), tg-row = l>>4) <- acc[p][j]
        #pragma unroll
        for (int j = 0; j < 4; ++j)
          *(f32x4*)(dw + ((l >> 4) << 10) + (((j << 4) + (l & 15)) << 4)) =
              acc[p][j];
        // scan 16 t: lane l = h, linear reads row g + l*16
        const int tb = t0 + p * 16;
        #pragma unroll
        for (int g = 0; g < 4; ++g) {
          const float4 v = *(const float4*)(dw + (g << 10) + (l << 4));
          const float cv[4] = {v.x, v.y, v.z, v.w};
          #pragma unroll
          for (int e = 0; e < 4; ++e) {
            if (tb + g * 4 + e < T_) {
              const float rst = sp ? 16.0f : 0.0f;
              mreg = fmaf(0.9f, mreg, cv[e]) - rst;   // bias already in acc
              sp = mreg > 16.0f;
              if (sp) cnt += 1.0f;
            }
          }
        }
      }
      #pragma unroll
      for (int i = 0; i < 8; ++i)
        #pragma unroll
        for (int j = 0; j < 4; ++j)
          acc[i][j] = (f32x4){biasj[j], biasj[j], biasj[j], biasj[j]};
    }

    __syncthreads();   // barA: all WBUF/xcur reads + dump/scan done

    if (do_stage) {
      // W-DMA round r+1 (L2-resident ws) + x cvt/ds_write into xnxt
      const char* wg = ws + (size_t)((((r + 1) & 7) << 1) + hf) * 32768;
      #pragma unroll
      for (int q = 0; q < 4; ++q) {
        const int o = (q * 256 + tid) * 16;
        lds_dma16(wg + o, smem + WBUF + o);
        lds_dma16(wg + 16384 + o, smem + WBUF + 16384 + o);
      }
      cvt_store(smem + xnxt, 2 * wv, l, a8[0]);
      cvt_store(smem + xnxt, 2 * wv + 1, l, a8[1]);
    }
    __syncthreads();   // barB: DMA vmcnt(0) + ds_writes visible
  }

  // ---- projection: cnt[h = wv*64+l] @ W2 -> out[b][c]
  const int hglob = hf * 256 + wv * 64 + l;
  #pragma unroll
  for (int c = 0; c < C_; ++c) {
    float p = cnt * W2[c * H_ + hglob];
    #pragma unroll
    for (int m = 32; m >= 1; m >>= 1) p += __shfl_xor(p, m, 64);
    if (l == 0) atomicAdd(&out[b * C_ + c], p);
  }
}

extern "C" void kernel_launch(void* const* d_in, const int* in_sizes, int n_in,
                              void* d_out, int out_size, void* d_ws,
                              size_t ws_size, hipStream_t stream) {
  (void)in_sizes; (void)n_in; (void)ws_size; (void)out_size;
  const float* x  = (const float*)d_in[0];
  const float* W1 = (const float*)d_in[1];
  const float* b1 = (const float*)d_in[2];
  const float* W2 = (const float*)d_in[3];
  const float* b2 = (const float*)d_in[4];
  float* out = (float*)d_out;
  char* ws = (char*)d_ws;   // 512 KB: 16 blocks x 32KB (ks x half, hi|lo)

  init_out_kernel<<<dim3((B_ * C_ + 255) / 256), dim3(256), 0, stream>>>(b2, out);
  split_w1_kernel<<<dim3(H_ * NKS * 4 / 256), dim3(256), 0, stream>>>(W1, ws);
  snn_mfma3<<<dim3(B_, 2), dim3(256), 0, stream>>>(x, ws, b1, W2, out);
}